// Round 1
// baseline (826.574 us; speedup 1.0000x reference)
//
#include <hip/hip_runtime.h>
#include <hip/hip_fp16.h>

#define TNUM 2048
#define DIMS 1024
#define HIDS 4096
#define NEXP 8
#define NROUT 7
#define ALPHAF 2.0f

typedef __attribute__((ext_vector_type(4))) float floatx4;
typedef _Float16 half8 __attribute__((ext_vector_type(8)));

static __device__ inline unsigned short f2h(float f) {
    return __half_as_ushort(__float2half(f));
}

// ---------------- router: fp32 logits, softmax, top-1 ----------------
__global__ __launch_bounds__(256) void router_kernel(
    const float* __restrict__ x, const float* __restrict__ wr,
    int* __restrict__ idx, float* __restrict__ wtok)
{
    int tok = blockIdx.x * 4 + (threadIdx.x >> 6);
    int lane = threadIdx.x & 63;
    const float* xp = x + (size_t)tok * DIMS;
    float acc[NEXP];
#pragma unroll
    for (int e = 0; e < NEXP; ++e) acc[e] = 0.f;
    for (int d = lane; d < DIMS; d += 64) {
        float xv = xp[d];
        const float* wrow = wr + d * NEXP;
#pragma unroll
        for (int e = 0; e < NEXP; ++e) acc[e] += xv * wrow[e];
    }
#pragma unroll
    for (int off = 32; off > 0; off >>= 1) {
#pragma unroll
        for (int e = 0; e < NEXP; ++e) acc[e] += __shfl_xor(acc[e], off, 64);
    }
    if (lane == 0) {
        float mx = acc[0];
#pragma unroll
        for (int e = 1; e < NEXP; ++e) mx = fmaxf(mx, acc[e]);
        float s = 0.f, pe[NEXP];
#pragma unroll
        for (int e = 0; e < NEXP; ++e) { pe[e] = __expf(acc[e] - mx); s += pe[e]; }
        int best = 0; float bv = acc[0];
#pragma unroll
        for (int e = 1; e < NEXP; ++e) if (acc[e] > bv) { bv = acc[e]; best = e; }
        idx[tok] = best;                       // may be 7 -> no routed expert
        wtok[tok] = ALPHAF * pe[best] / s;     // ALPHA * top1 prob
    }
}

__global__ void zero_counts_kernel(int* counts) {
    if (threadIdx.x < NROUT) counts[threadIdx.x] = 0;
}

__global__ __launch_bounds__(256) void build_lists_kernel(
    const int* __restrict__ idx, int* __restrict__ counts, int* __restrict__ lists)
{
    int t = blockIdx.x * 256 + threadIdx.x;
    int e = idx[t];
    if (e < NROUT) {
        int pos = atomicAdd(&counts[e], 1);
        lists[e * TNUM + pos] = t;
    }
}

// ---------------- up/gate + silu, grouped GEMM, h -> ws (f16) ----------------
// C[m][n] tiles 64x64, K = DIMS. A = gathered x rows (f16 cast), B = w (k-major,
// transposed to [n][k] in LDS at staging). 4 waves, each 16 rows x 64 cols.
template<bool ROUTED>
__global__ __launch_bounds__(256) void upgate_kernel(
    const float* __restrict__ x,
    const float* __restrict__ wu_base,
    const float* __restrict__ wg_base,
    unsigned short* __restrict__ hbuf,
    const int* __restrict__ lists,
    const int* __restrict__ counts)
{
    int e = ROUTED ? blockIdx.z : 0;
    int cnt = ROUTED ? counts[e] : TNUM;
    int m0 = blockIdx.y * 64;
    if (m0 >= cnt) return;
    int n0 = blockIdx.x * 64;
    const float* WU = wu_base + (ROUTED ? (size_t)e * DIMS * HIDS : 0);
    const float* WG = wg_base + (ROUTED ? (size_t)e * DIMS * HIDS : 0);

    __shared__ unsigned short As[64 * 72];   // [m][k], stride 72 to kill conflicts
    __shared__ unsigned short BsU[64 * 72];  // [n][k]
    __shared__ unsigned short BsG[64 * 72];  // [n][k]
    __shared__ int rowTok[64];

    int t = threadIdx.x;
    if (t < 64) {
        int i = m0 + t;
        rowTok[t] = (i < cnt) ? (ROUTED ? lists[e * TNUM + i] : i) : -1;
    }
    __syncthreads();

    int lane = t & 63;
    int wv = t >> 6;
    int ar = t >> 2;             // A stage: row
    int ac = (t & 3) * 16;       // A stage: col chunk (16 elems)
    int tokA = rowTok[ar]; if (tokA < 0) tokA = 0;
    const float* xrow = x + (size_t)tokA * DIMS + ac;
    int bk = t >> 2;             // B stage: k row
    int bn = (t & 3) * 16;       // B stage: n chunk

    floatx4 accU[4], accG[4];
#pragma unroll
    for (int c = 0; c < 4; ++c) {
        accU[c] = (floatx4){0.f, 0.f, 0.f, 0.f};
        accG[c] = (floatx4){0.f, 0.f, 0.f, 0.f};
    }

    for (int k0 = 0; k0 < DIMS; k0 += 64) {
        // ---- stage A (x rows, f32 -> f16) ----
        float av[16];
        *reinterpret_cast<float4*>(&av[0])  = *reinterpret_cast<const float4*>(xrow + k0);
        *reinterpret_cast<float4*>(&av[4])  = *reinterpret_cast<const float4*>(xrow + k0 + 4);
        *reinterpret_cast<float4*>(&av[8])  = *reinterpret_cast<const float4*>(xrow + k0 + 8);
        *reinterpret_cast<float4*>(&av[12]) = *reinterpret_cast<const float4*>(xrow + k0 + 12);
        unsigned int pk[8];
#pragma unroll
        for (int j = 0; j < 8; ++j)
            pk[j] = (unsigned int)f2h(av[2*j]) | ((unsigned int)f2h(av[2*j+1]) << 16);
        *reinterpret_cast<uint4*>(&As[ar * 72 + ac])     = make_uint4(pk[0], pk[1], pk[2], pk[3]);
        *reinterpret_cast<uint4*>(&As[ar * 72 + ac + 8]) = make_uint4(pk[4], pk[5], pk[6], pk[7]);

        // ---- stage B (weights, transpose to [n][k]) ----
        {
            const float* bp = WU + (size_t)(k0 + bk) * HIDS + n0 + bn;
            float bv[16];
            *reinterpret_cast<float4*>(&bv[0])  = *reinterpret_cast<const float4*>(bp);
            *reinterpret_cast<float4*>(&bv[4])  = *reinterpret_cast<const float4*>(bp + 4);
            *reinterpret_cast<float4*>(&bv[8])  = *reinterpret_cast<const float4*>(bp + 8);
            *reinterpret_cast<float4*>(&bv[12]) = *reinterpret_cast<const float4*>(bp + 12);
            unsigned short* d = &BsU[bn * 72 + bk];
#pragma unroll
            for (int j = 0; j < 16; ++j) d[j * 72] = f2h(bv[j]);
        }
        {
            const float* bp = WG + (size_t)(k0 + bk) * HIDS + n0 + bn;
            float bv[16];
            *reinterpret_cast<float4*>(&bv[0])  = *reinterpret_cast<const float4*>(bp);
            *reinterpret_cast<float4*>(&bv[4])  = *reinterpret_cast<const float4*>(bp + 4);
            *reinterpret_cast<float4*>(&bv[8])  = *reinterpret_cast<const float4*>(bp + 8);
            *reinterpret_cast<float4*>(&bv[12]) = *reinterpret_cast<const float4*>(bp + 12);
            unsigned short* d = &BsG[bn * 72 + bk];
#pragma unroll
            for (int j = 0; j < 16; ++j) d[j * 72] = f2h(bv[j]);
        }
        __syncthreads();

        // ---- MFMA ----
#pragma unroll
        for (int kk = 0; kk < 2; ++kk) {
            half8 a = *reinterpret_cast<const half8*>(
                &As[(wv * 16 + (lane & 15)) * 72 + kk * 32 + (lane >> 4) * 8]);
#pragma unroll
            for (int c = 0; c < 4; ++c) {
                half8 bu = *reinterpret_cast<const half8*>(
                    &BsU[(c * 16 + (lane & 15)) * 72 + kk * 32 + (lane >> 4) * 8]);
                accU[c] = __builtin_amdgcn_mfma_f32_16x16x32_f16(a, bu, accU[c], 0, 0, 0);
                half8 bg = *reinterpret_cast<const half8*>(
                    &BsG[(c * 16 + (lane & 15)) * 72 + kk * 32 + (lane >> 4) * 8]);
                accG[c] = __builtin_amdgcn_mfma_f32_16x16x32_f16(a, bg, accG[c], 0, 0, 0);
            }
        }
        __syncthreads();
    }

    // ---- epilogue: h = up * silu(gate), store f16 ----
    int colb = lane & 15, rq = lane >> 4;
#pragma unroll
    for (int r = 0; r < 4; ++r) {
        int m = wv * 16 + rq * 4 + r;
        int tok = rowTok[m];
        if (tok < 0) continue;
        unsigned short* hp = hbuf + (size_t)tok * HIDS + n0 + colb;
#pragma unroll
        for (int c = 0; c < 4; ++c) {
            float u = accU[c][r], g = accG[c][r];
            float h = u * (g / (1.f + __expf(-g)));
            hp[c * 16] = f2h(h);
        }
    }
}

// ---------------- down projection, grouped GEMM, scatter to out ----------------
template<bool ROUTED>
__global__ __launch_bounds__(256) void down_kernel(
    const unsigned short* __restrict__ hbuf,
    const float* __restrict__ wd_base,
    float* __restrict__ out,
    const int* __restrict__ lists,
    const int* __restrict__ counts,
    const float* __restrict__ wtok)
{
    int e = ROUTED ? blockIdx.z : 0;
    int cnt = ROUTED ? counts[e] : TNUM;
    int m0 = blockIdx.y * 64;
    if (m0 >= cnt) return;
    int n0 = blockIdx.x * 64;
    const float* WD = wd_base + (ROUTED ? (size_t)e * HIDS * DIMS : 0);

    __shared__ unsigned short As[64 * 72];
    __shared__ unsigned short Bs[64 * 72];
    __shared__ int rowTok[64];

    int t = threadIdx.x;
    if (t < 64) {
        int i = m0 + t;
        rowTok[t] = (i < cnt) ? (ROUTED ? lists[e * TNUM + i] : i) : -1;
    }
    __syncthreads();

    int lane = t & 63;
    int wv = t >> 6;
    int ar = t >> 2;
    int ac = (t & 3) * 16;
    int tokA = rowTok[ar]; if (tokA < 0) tokA = 0;
    const unsigned short* hrow = hbuf + (size_t)tokA * HIDS + ac;
    int bk = t >> 2;
    int bn = (t & 3) * 16;

    floatx4 acc[4];
#pragma unroll
    for (int c = 0; c < 4; ++c) acc[c] = (floatx4){0.f, 0.f, 0.f, 0.f};

    for (int k0 = 0; k0 < HIDS; k0 += 64) {
        // ---- stage A (h rows, already f16: straight copy) ----
        uint4 pa = *reinterpret_cast<const uint4*>(hrow + k0);
        uint4 pb = *reinterpret_cast<const uint4*>(hrow + k0 + 8);
        *reinterpret_cast<uint4*>(&As[ar * 72 + ac])     = pa;
        *reinterpret_cast<uint4*>(&As[ar * 72 + ac + 8]) = pb;

        // ---- stage B (w_down, transpose to [n][k]) ----
        {
            const float* bp = WD + (size_t)(k0 + bk) * DIMS + n0 + bn;
            float bv[16];
            *reinterpret_cast<float4*>(&bv[0])  = *reinterpret_cast<const float4*>(bp);
            *reinterpret_cast<float4*>(&bv[4])  = *reinterpret_cast<const float4*>(bp + 4);
            *reinterpret_cast<float4*>(&bv[8])  = *reinterpret_cast<const float4*>(bp + 8);
            *reinterpret_cast<float4*>(&bv[12]) = *reinterpret_cast<const float4*>(bp + 12);
            unsigned short* d = &Bs[bn * 72 + bk];
#pragma unroll
            for (int j = 0; j < 16; ++j) d[j * 72] = f2h(bv[j]);
        }
        __syncthreads();

#pragma unroll
        for (int kk = 0; kk < 2; ++kk) {
            half8 a = *reinterpret_cast<const half8*>(
                &As[(wv * 16 + (lane & 15)) * 72 + kk * 32 + (lane >> 4) * 8]);
#pragma unroll
            for (int c = 0; c < 4; ++c) {
                half8 b = *reinterpret_cast<const half8*>(
                    &Bs[(c * 16 + (lane & 15)) * 72 + kk * 32 + (lane >> 4) * 8]);
                acc[c] = __builtin_amdgcn_mfma_f32_16x16x32_f16(a, b, acc[c], 0, 0, 0);
            }
        }
        __syncthreads();
    }

    // ---- epilogue ----
    int colb = lane & 15, rq = lane >> 4;
#pragma unroll
    for (int r = 0; r < 4; ++r) {
        int m = wv * 16 + rq * 4 + r;
        int tok = rowTok[m];
        if (tok < 0) continue;
        float* op = out + (size_t)tok * DIMS + n0 + colb;
        if (ROUTED) {
            float scale = wtok[tok];
#pragma unroll
            for (int c = 0; c < 4; ++c) op[c * 16] += scale * acc[c][r];  // rows disjoint -> safe RMW
        } else {
#pragma unroll
            for (int c = 0; c < 4; ++c) op[c * 16] = acc[c][r];           // shared pass writes all rows
        }
    }
}

extern "C" void kernel_launch(void* const* d_in, const int* in_sizes, int n_in,
                              void* d_out, int out_size, void* d_ws, size_t ws_size,
                              hipStream_t stream)
{
    const float* x  = (const float*)d_in[0];
    const float* wr = (const float*)d_in[1];
    const float* wu = (const float*)d_in[2];
    const float* wg = (const float*)d_in[3];
    const float* wd = (const float*)d_in[4];
    const float* su = (const float*)d_in[5];
    const float* sg = (const float*)d_in[6];
    const float* sd = (const float*)d_in[7];
    float* out = (float*)d_out;

    char* ws = (char*)d_ws;
    unsigned short* hbuf = (unsigned short*)ws;                 // TNUM*HIDS f16 = 16 MB
    float* wtok = (float*)(ws + (size_t)TNUM * HIDS * 2);
    int* idx    = (int*)(wtok + TNUM);
    int* counts = (int*)(idx + TNUM);
    int* lists  = counts + 16;

    router_kernel<<<TNUM / 4, 256, 0, stream>>>(x, wr, idx, wtok);
    zero_counts_kernel<<<1, 64, 0, stream>>>(counts);
    build_lists_kernel<<<TNUM / 256, 256, 0, stream>>>(idx, counts, lists);

    // shared expert first (writes every row of out), routed second (RMW-adds)
    dim3 gridUGs(HIDS / 64, TNUM / 64, 1);
    upgate_kernel<false><<<gridUGs, 256, 0, stream>>>(x, su, sg, hbuf, nullptr, nullptr);
    dim3 gridDs(DIMS / 64, TNUM / 64, 1);
    down_kernel<false><<<gridDs, 256, 0, stream>>>(hbuf, sd, out, nullptr, nullptr, nullptr);

    dim3 gridUGr(HIDS / 64, TNUM / 64, NROUT);
    upgate_kernel<true><<<gridUGr, 256, 0, stream>>>(x, wu, wg, hbuf, lists, counts);
    dim3 gridDr(DIMS / 64, TNUM / 64, NROUT);
    down_kernel<true><<<gridDr, 256, 0, stream>>>(hbuf, wd, out, lists, counts, wtok);
}

// Round 2
// 760.396 us; speedup vs baseline: 1.0870x; 1.0870x over previous
//
#include <hip/hip_runtime.h>
#include <hip/hip_fp16.h>

#define TNUM 2048
#define DIMS 1024
#define HIDS 4096
#define NEXP 8
#define NROUT 7
#define ALPHAF 2.0f

typedef __attribute__((ext_vector_type(4))) float floatx4;
typedef _Float16 half8 __attribute__((ext_vector_type(8)));
typedef unsigned short ushort_t;

static __device__ __forceinline__ ushort_t f2h(float f) {
    return __half_as_ushort(__float2half(f));
}

// async 16B global -> LDS. lds base must be wave-uniform; HW adds lane*16.
static __device__ __forceinline__ void async16(ushort_t* lds, const ushort_t* g) {
#if __has_builtin(__builtin_amdgcn_global_load_lds)
    __builtin_amdgcn_global_load_lds(
        (const __attribute__((address_space(1))) unsigned int*)g,
        (__attribute__((address_space(3))) unsigned int*)lds, 16, 0, 0);
#else
    int l = threadIdx.x & 63;
    *(uint4*)(lds + l * 8) = *(const uint4*)g;
#endif
}

// ---------------- router: fp32 logits, softmax, top-1 ----------------
__global__ __launch_bounds__(256) void router_kernel(
    const float* __restrict__ x, const float* __restrict__ wr,
    int* __restrict__ idx, float* __restrict__ wtok)
{
    int tok = blockIdx.x * 4 + (threadIdx.x >> 6);
    int lane = threadIdx.x & 63;
    const float* xp = x + (size_t)tok * DIMS;
    float acc[NEXP];
#pragma unroll
    for (int e = 0; e < NEXP; ++e) acc[e] = 0.f;
    for (int d = lane; d < DIMS; d += 64) {
        float xv = xp[d];
        const float* wrow = wr + d * NEXP;
#pragma unroll
        for (int e = 0; e < NEXP; ++e) acc[e] += xv * wrow[e];
    }
#pragma unroll
    for (int off = 32; off > 0; off >>= 1) {
#pragma unroll
        for (int e = 0; e < NEXP; ++e) acc[e] += __shfl_xor(acc[e], off, 64);
    }
    if (lane == 0) {
        float mx = acc[0];
#pragma unroll
        for (int e = 1; e < NEXP; ++e) mx = fmaxf(mx, acc[e]);
        float s = 0.f, pe[NEXP];
#pragma unroll
        for (int e = 0; e < NEXP; ++e) { pe[e] = __expf(acc[e] - mx); s += pe[e]; }
        int best = 0; float bv = acc[0];
#pragma unroll
        for (int e = 1; e < NEXP; ++e) if (acc[e] > bv) { bv = acc[e]; best = e; }
        idx[tok] = best;                       // may be 7 -> no routed expert
        wtok[tok] = ALPHAF * pe[best] / s;     // ALPHA * top1 prob
    }
}

__global__ void zero_counts_kernel(int* counts) {
    if (threadIdx.x < NROUT) counts[threadIdx.x] = 0;
}

__global__ __launch_bounds__(256) void build_lists_kernel(
    const int* __restrict__ idx, int* __restrict__ counts, int* __restrict__ lists)
{
    int t = blockIdx.x * 256 + threadIdx.x;
    int e = idx[t];
    if (e < NROUT) {
        int pos = atomicAdd(&counts[e], 1);
        lists[e * TNUM + pos] = t;
    }
}

// ---------------- x fp32 -> f16 ----------------
__global__ __launch_bounds__(256) void x2h_kernel(
    const float* __restrict__ x, ushort_t* __restrict__ x16)
{
    int i = (blockIdx.x * 256 + threadIdx.x) * 4;
    float4 v = *(const float4*)(x + i);
    ushort_t tmp[4] = { f2h(v.x), f2h(v.y), f2h(v.z), f2h(v.w) };
    *(uint2*)(x16 + i) = *(const uint2*)tmp;
}

// ---------------- weight repack: f32 [K][N] -> f16 [n'][K] ----------------
// up/gate interleaved: wugT[e] has row 2n = up col n, row 2n+1 = gate col n.
// Expert 7 = shared. wdT[e] = down weights [DIMS][HIDS] f16 (e7 = shared).
__global__ __launch_bounds__(256) void repack_kernel(
    const float* __restrict__ wu, const float* __restrict__ wg, const float* __restrict__ wd,
    const float* __restrict__ su, const float* __restrict__ sg, const float* __restrict__ sd,
    ushort_t* __restrict__ wugT, ushort_t* __restrict__ wdT)
{
    int z = blockIdx.z;
    const float* src; ushort_t* dst; int K, N, rmul, radd;
    if (z < 7)        { src = wu + (size_t)z * DIMS * HIDS;        dst = wugT + (size_t)z * 2 * HIDS * DIMS; K = DIMS; N = HIDS; rmul = 2; radd = 0; }
    else if (z < 14)  { src = wg + (size_t)(z - 7) * DIMS * HIDS;  dst = wugT + (size_t)(z - 7) * 2 * HIDS * DIMS; K = DIMS; N = HIDS; rmul = 2; radd = 1; }
    else if (z < 21)  { src = wd + (size_t)(z - 14) * HIDS * DIMS; dst = wdT + (size_t)(z - 14) * DIMS * HIDS; K = HIDS; N = DIMS; rmul = 1; radd = 0; }
    else if (z == 21) { src = su; dst = wugT + (size_t)7 * 2 * HIDS * DIMS; K = DIMS; N = HIDS; rmul = 2; radd = 0; }
    else if (z == 22) { src = sg; dst = wugT + (size_t)7 * 2 * HIDS * DIMS; K = DIMS; N = HIDS; rmul = 2; radd = 1; }
    else              { src = sd; dst = wdT + (size_t)7 * DIMS * HIDS; K = HIDS; N = DIMS; rmul = 1; radd = 0; }

    int n0 = blockIdx.x * 64, k0 = blockIdx.y * 64;
    if (n0 >= N || k0 >= K) return;

    __shared__ float T[64][65];
    int t = threadIdx.x;
    int lk = t >> 4, ln4 = (t & 15) * 4;
#pragma unroll
    for (int p = 0; p < 4; ++p) {
        float4 v = *(const float4*)(src + (size_t)(k0 + p * 16 + lk) * N + n0 + ln4);
        T[p * 16 + lk][ln4]     = v.x;
        T[p * 16 + lk][ln4 + 1] = v.y;
        T[p * 16 + lk][ln4 + 2] = v.z;
        T[p * 16 + lk][ln4 + 3] = v.w;
    }
    __syncthreads();
    int rn = t >> 2, kc = (t & 3) * 16;
    ushort_t tmp[16];
#pragma unroll
    for (int j = 0; j < 16; ++j) tmp[j] = f2h(T[kc + j][rn]);
    ushort_t* dp = dst + (size_t)(rmul * (n0 + rn) + radd) * K + k0 + kc;
    *(uint4*)dp       = *(const uint4*)&tmp[0];
    *(uint4*)(dp + 8) = *(const uint4*)&tmp[8];
}

// ---------------- GEMM, 128x128 tile, BK=64, f16, global_load_lds ----------------
// MODE 0: up/gate (K=DIMS, N=8192 interleaved u/g) -> h = u*silu(g), f16
// MODE 1: down shared (K=HIDS, N=DIMS) -> out = acc
// MODE 2: down routed (K=HIDS, N=DIMS) -> out += wtok*acc
template<int MODE>
__global__ __launch_bounds__(256) void gemm_kernel(
    const ushort_t* __restrict__ Abase,
    const ushort_t* __restrict__ Bbase,
    ushort_t* __restrict__ hs, ushort_t* __restrict__ hr,
    float* __restrict__ out,
    const int* __restrict__ lists, const int* __restrict__ counts,
    const float* __restrict__ wtok)
{
    constexpr int K = (MODE == 0) ? DIMS : HIDS;
    int e = blockIdx.z;
    bool routed = (MODE == 0) ? (e < NROUT) : (MODE == 2);
    int cnt = routed ? counts[e] : TNUM;
    int m0 = blockIdx.y * 128;
    if (m0 >= cnt) return;
    int n0 = blockIdx.x * 128;
    const ushort_t* Bm = Bbase +
        (MODE == 0 ? (size_t)e * 2 * HIDS * DIMS
                   : (MODE == 2 ? (size_t)e * DIMS * HIDS : 0));

    __shared__ ushort_t As[128 * 64];
    __shared__ ushort_t Bs[128 * 64];
    __shared__ int rowTok[128];

    int t = threadIdx.x;
    if (t < 128) {
        int i = m0 + t;
        rowTok[t] = (i < cnt) ? (routed ? lists[e * TNUM + i] : i) : -1;
    }
    __syncthreads();

    int w = t >> 6, l = t & 63;
    const ushort_t* gA[4]; const ushort_t* gB[4];
    ushort_t* lA[4]; ushort_t* lB[4];
#pragma unroll
    for (int p = 0; p < 4; ++p) {
        int slot = p * 256 + t;
        int row = slot >> 3, ch = slot & 7;
        int tok = rowTok[row]; if (tok < 0) tok = 0;
        gA[p] = Abase + (size_t)tok * K + ch * 8;
        gB[p] = Bm + (size_t)(n0 + row) * K + ch * 8;
        lA[p] = &As[(p * 256 + w * 64) * 8];
        lB[p] = &Bs[(p * 256 + w * 64) * 8];
    }

    floatx4 acc[4][4];
#pragma unroll
    for (int i = 0; i < 4; ++i)
#pragma unroll
        for (int j = 0; j < 4; ++j) acc[i][j] = (floatx4){0.f, 0.f, 0.f, 0.f};

    int wr = (w >> 1) * 64, wc = (w & 1) * 64;
    int fr = l & 15, fk = (l >> 4) * 8;

    for (int k0 = 0; k0 < K; k0 += 64) {
#pragma unroll
        for (int p = 0; p < 4; ++p) {
            async16(lA[p], gA[p]); gA[p] += 64;
            async16(lB[p], gB[p]); gB[p] += 64;
        }
        __syncthreads();
#pragma unroll
        for (int kk = 0; kk < 2; ++kk) {
            half8 a[4], b[4];
#pragma unroll
            for (int i = 0; i < 4; ++i)
                a[i] = *(const half8*)&As[(wr + i * 16 + fr) * 64 + kk * 32 + fk];
#pragma unroll
            for (int j = 0; j < 4; ++j)
                b[j] = *(const half8*)&Bs[(wc + j * 16 + fr) * 64 + kk * 32 + fk];
#pragma unroll
            for (int i = 0; i < 4; ++i)
#pragma unroll
                for (int j = 0; j < 4; ++j)
                    acc[i][j] = __builtin_amdgcn_mfma_f32_16x16x32_f16(a[i], b[j], acc[i][j], 0, 0, 0);
        }
        __syncthreads();
    }

    // ---- epilogue ----
    int cq = l & 15, rq = (l >> 4) * 4;
    if (MODE == 0) {
        ushort_t* hdst = (e == NROUT) ? hs : hr;
#pragma unroll
        for (int i = 0; i < 4; ++i) {
#pragma unroll
            for (int r = 0; r < 4; ++r) {
                int m = wr + i * 16 + rq + r;
                int tok = rowTok[m];
#pragma unroll
                for (int j = 0; j < 4; ++j) {
                    float v = acc[i][j][r];
                    float pv = __shfl_xor(v, 1, 64);  // partner column (u<->g)
                    if (((l & 1) == 0) && tok >= 0) {
                        float g = pv;                 // even col = u, odd = g
                        float h = v * (g / (1.f + __expf(-g)));
                        int ncol = n0 + wc + j * 16 + cq;      // even
                        hdst[(size_t)tok * HIDS + (ncol >> 1)] = f2h(h);
                    }
                }
            }
        }
    } else {
#pragma unroll
        for (int i = 0; i < 4; ++i) {
#pragma unroll
            for (int r = 0; r < 4; ++r) {
                int m = wr + i * 16 + rq + r;
                int tok = rowTok[m];
                if (tok < 0) continue;
                float* op = out + (size_t)tok * DIMS + n0 + wc + cq;
                if (MODE == 1) {
#pragma unroll
                    for (int j = 0; j < 4; ++j) op[j * 16] = acc[i][j][r];
                } else {
                    float s = wtok[tok];
#pragma unroll
                    for (int j = 0; j < 4; ++j) op[j * 16] += s * acc[i][j][r];
                }
            }
        }
    }
}

extern "C" void kernel_launch(void* const* d_in, const int* in_sizes, int n_in,
                              void* d_out, int out_size, void* d_ws, size_t ws_size,
                              hipStream_t stream)
{
    const float* x  = (const float*)d_in[0];
    const float* wr = (const float*)d_in[1];
    const float* wu = (const float*)d_in[2];
    const float* wg = (const float*)d_in[3];
    const float* wd = (const float*)d_in[4];
    const float* su = (const float*)d_in[5];
    const float* sg = (const float*)d_in[6];
    const float* sd = (const float*)d_in[7];
    float* out = (float*)d_out;

    char* ws = (char*)d_ws;
    size_t off = 0;
    ushort_t* wugT = (ushort_t*)(ws + off); off += (size_t)NEXP * 2 * HIDS * DIMS * 2;  // 128 MB
    ushort_t* wdT  = (ushort_t*)(ws + off); off += (size_t)NEXP * DIMS * HIDS * 2;      //  64 MB
    ushort_t* x16  = (ushort_t*)(ws + off); off += (size_t)TNUM * DIMS * 2;             //   4 MB
    ushort_t* hsh  = (ushort_t*)(ws + off); off += (size_t)TNUM * HIDS * 2;             //  16 MB
    ushort_t* hrt  = (ushort_t*)(ws + off); off += (size_t)TNUM * HIDS * 2;             //  16 MB
    float* wtok    = (float*)(ws + off);    off += TNUM * 4;
    int* idx       = (int*)(ws + off);      off += TNUM * 4;
    int* counts    = (int*)(ws + off);      off += 64;
    int* lists     = (int*)(ws + off);      off += (size_t)NROUT * TNUM * 4;

    router_kernel<<<TNUM / 4, 256, 0, stream>>>(x, wr, idx, wtok);
    zero_counts_kernel<<<1, 64, 0, stream>>>(counts);
    build_lists_kernel<<<TNUM / 256, 256, 0, stream>>>(idx, counts, lists);
    x2h_kernel<<<TNUM * DIMS / 1024, 256, 0, stream>>>(x, x16);
    repack_kernel<<<dim3(64, 64, 24), 256, 0, stream>>>(wu, wg, wd, su, sg, sd, wugT, wdT);

    // up/gate + fused SwiGLU for all 8 experts (7 routed + shared)
    gemm_kernel<0><<<dim3(2 * HIDS / 128, TNUM / 128, NEXP), 256, 0, stream>>>(
        x16, wugT, hsh, hrt, nullptr, lists, counts, nullptr);
    // down shared: writes every row of out
    gemm_kernel<1><<<dim3(DIMS / 128, TNUM / 128, 1), 256, 0, stream>>>(
        hsh, wdT + (size_t)NROUT * DIMS * HIDS, nullptr, nullptr, out, nullptr, nullptr, nullptr);
    // down routed: RMW-adds on disjoint token rows
    gemm_kernel<2><<<dim3(DIMS / 128, TNUM / 128, NROUT), 256, 0, stream>>>(
        hrt, wdT, nullptr, nullptr, out, lists, counts, wtok);
}

// Round 3
// 696.439 us; speedup vs baseline: 1.1869x; 1.0918x over previous
//
#include <hip/hip_runtime.h>
#include <hip/hip_fp16.h>

#define TNUM 2048
#define DIMS 1024
#define HIDS 4096
#define NEXP 8
#define NROUT 7
#define ALPHAF 2.0f

typedef __attribute__((ext_vector_type(4))) float floatx4;
typedef _Float16 half8 __attribute__((ext_vector_type(8)));
typedef unsigned short ushort_t;

static __device__ __forceinline__ ushort_t f2h(float f) {
    return __half_as_ushort(__float2half(f));
}

// async 16B global -> LDS. lds base wave-uniform; HW adds lane*16.
static __device__ __forceinline__ void async16(ushort_t* lds, const ushort_t* g) {
#if __has_builtin(__builtin_amdgcn_global_load_lds)
    __builtin_amdgcn_global_load_lds(
        (const __attribute__((address_space(1))) unsigned int*)g,
        (__attribute__((address_space(3))) unsigned int*)lds, 16, 0, 0);
#else
    int l = threadIdx.x & 63;
    *(uint4*)(lds + l * 8) = *(const uint4*)g;
#endif
}

// ---------------- router: fp32 logits, softmax, top-1 ----------------
// Trick: best==7 (no routed expert) -> assign expert 0 with weight 0, so every
// token belongs to exactly one routed group (enables single-pass down GEMM).
__global__ __launch_bounds__(256) void router_kernel(
    const float* __restrict__ x, const float* __restrict__ wr,
    int* __restrict__ idx, float* __restrict__ wtok)
{
    int tok = blockIdx.x * 4 + (threadIdx.x >> 6);
    int lane = threadIdx.x & 63;
    const float* xp = x + (size_t)tok * DIMS;
    float acc[NEXP];
#pragma unroll
    for (int e = 0; e < NEXP; ++e) acc[e] = 0.f;
    for (int d = lane; d < DIMS; d += 64) {
        float xv = xp[d];
        const float* wrow = wr + d * NEXP;
#pragma unroll
        for (int e = 0; e < NEXP; ++e) acc[e] += xv * wrow[e];
    }
#pragma unroll
    for (int off = 32; off > 0; off >>= 1) {
#pragma unroll
        for (int e = 0; e < NEXP; ++e) acc[e] += __shfl_xor(acc[e], off, 64);
    }
    if (lane == 0) {
        float mx = acc[0];
#pragma unroll
        for (int e = 1; e < NEXP; ++e) mx = fmaxf(mx, acc[e]);
        float s = 0.f, pe[NEXP];
#pragma unroll
        for (int e = 0; e < NEXP; ++e) { pe[e] = __expf(acc[e] - mx); s += pe[e]; }
        int best = 0; float bv = acc[0];
#pragma unroll
        for (int e = 1; e < NEXP; ++e) if (acc[e] > bv) { bv = acc[e]; best = e; }
        if (best == NROUT) { idx[tok] = 0; wtok[tok] = 0.f; }
        else               { idx[tok] = best; wtok[tok] = ALPHAF * pe[best] / s; }
    }
}

__global__ void zero_counts_kernel(int* counts) {
    if (threadIdx.x < NROUT) counts[threadIdx.x] = 0;
}

__global__ __launch_bounds__(256) void build_lists_kernel(
    const int* __restrict__ idx, int* __restrict__ counts, int* __restrict__ lists)
{
    int t = blockIdx.x * 256 + threadIdx.x;
    int e = idx[t];
    int pos = atomicAdd(&counts[e], 1);
    lists[e * TNUM + pos] = t;
}

// ---------------- x fp32 -> f16 ----------------
__global__ __launch_bounds__(256) void x2h_kernel(
    const float* __restrict__ x, ushort_t* __restrict__ x16)
{
    int i = (blockIdx.x * 256 + threadIdx.x) * 4;
    float4 v = *(const float4*)(x + i);
    ushort_t tmp[4] = { f2h(v.x), f2h(v.y), f2h(v.z), f2h(v.w) };
    *(uint2*)(x16 + i) = *(const uint2*)tmp;
}

// ---------------- weight repack: f32 [K][N] -> f16 [R(n)][K] ----------------
// up/gate layout per expert (8192 rows x 1024): per 64-row group G,
// rows G*64+0..31  = up  cols G*32+0..31, rows G*64+32..63 = gate cols.
// down layout per expert: plain [DIMS n][HIDS k]. Expert 7 = shared.
__global__ __launch_bounds__(256) void repack_kernel(
    const float* __restrict__ wu, const float* __restrict__ wg, const float* __restrict__ wd,
    const float* __restrict__ su, const float* __restrict__ sg, const float* __restrict__ sd,
    ushort_t* __restrict__ wugT, ushort_t* __restrict__ wdT)
{
    int g = blockIdx.x;
    const float* src; ushort_t* dst; int N, K, gateAdd; bool ug;
    int nt, kt;
    if (g < 16384) {                      // up/gate slices: 64 n-tiles x 16 k-tiles
        int slice = g >> 10, r = g & 1023;
        nt = r >> 4; kt = r & 15;
        K = DIMS; N = HIDS; ug = true;
        if (slice < 7)        { src = wu + (size_t)slice * DIMS * HIDS;       dst = wugT + (size_t)slice * 2 * HIDS * DIMS; gateAdd = 0; }
        else if (slice < 14)  { src = wg + (size_t)(slice - 7) * DIMS * HIDS; dst = wugT + (size_t)(slice - 7) * 2 * HIDS * DIMS; gateAdd = 32; }
        else if (slice == 14) { src = su; dst = wugT + (size_t)7 * 2 * HIDS * DIMS; gateAdd = 0; }
        else                  { src = sg; dst = wugT + (size_t)7 * 2 * HIDS * DIMS; gateAdd = 32; }
    } else {                              // down slices: 16 n-tiles x 64 k-tiles
        int gd = g - 16384; int slice = gd >> 10, r = gd & 1023;
        nt = r & 15; kt = r >> 4;
        K = HIDS; N = DIMS; ug = false; gateAdd = 0;
        if (slice < 7) { src = wd + (size_t)slice * HIDS * DIMS; dst = wdT + (size_t)slice * DIMS * HIDS; }
        else           { src = sd;                               dst = wdT + (size_t)7 * DIMS * HIDS; }
    }
    int n0 = nt * 64, k0 = kt * 64;

    __shared__ ushort_t T[64 * 66];   // [n][k], ldk=66 shorts (4-way worst case)
    int t = threadIdx.x;
    int kr = t >> 2, nc = (t & 3) * 16;
    const float* sp = src + (size_t)(k0 + kr) * N + n0 + nc;
    float v[16];
    *(float4*)&v[0]  = *(const float4*)sp;
    *(float4*)&v[4]  = *(const float4*)(sp + 4);
    *(float4*)&v[8]  = *(const float4*)(sp + 8);
    *(float4*)&v[12] = *(const float4*)(sp + 12);
#pragma unroll
    for (int j = 0; j < 16; ++j) T[(nc + j) * 66 + kr] = f2h(v[j]);
    __syncthreads();

    int rn = t >> 2, kc = (t & 3) * 16;
    ushort_t ov[16];
#pragma unroll
    for (int j = 0; j < 8; ++j)
        *(unsigned int*)&ov[2 * j] = *(const unsigned int*)&T[rn * 66 + kc + 2 * j];
    int n = n0 + rn;
    size_t R = ug ? (size_t)(((n >> 5) << 6) + (n & 31) + gateAdd) : (size_t)n;
    ushort_t* dp = dst + R * K + k0 + kc;
    *(uint4*)dp       = *(const uint4*)&ov[0];
    *(uint4*)(dp + 8) = *(const uint4*)&ov[8];
}

// ---------------- up/gate GEMM 128x128, BK=64, swizzled LDS ----------------
// z = expert (7 = shared over all tokens). Epilogue: h = [wtok *] u*silu(g),
// written to hcat[tok][8192]: shared half [0,4096), routed half [4096,8192).
__global__ __launch_bounds__(256) void upgate_gemm(
    const ushort_t* __restrict__ x16, const ushort_t* __restrict__ wugT,
    ushort_t* __restrict__ hcat,
    const int* __restrict__ lists, const int* __restrict__ counts,
    const float* __restrict__ wtok)
{
    int e = blockIdx.z;
    bool routed = e < NROUT;
    int cnt = routed ? counts[e] : TNUM;
    int m0 = blockIdx.y * 128;
    if (m0 >= cnt) return;
    int n0 = blockIdx.x * 128;
    const ushort_t* B = wugT + (size_t)e * 2 * HIDS * DIMS;

    __shared__ ushort_t As[128 * 64];
    __shared__ ushort_t Bs[128 * 64];
    __shared__ int rowTok[128];
    int t = threadIdx.x;
    if (t < 128) {
        int i = m0 + t;
        rowTok[t] = (i < cnt) ? (routed ? lists[e * TNUM + i] : i) : -1;
    }
    __syncthreads();

    int w = t >> 6, l = t & 63;
    const ushort_t *gA[4], *gB[4]; ushort_t *lA[4], *lB[4];
#pragma unroll
    for (int p = 0; p < 4; ++p) {
        int slot = p * 256 + t, row = slot >> 3, ch = (slot & 7) ^ (row & 7);
        int tok = rowTok[row]; if (tok < 0) tok = 0;
        gA[p] = x16 + (size_t)tok * DIMS + ch * 8;
        gB[p] = B + (size_t)(n0 + row) * DIMS + ch * 8;
        lA[p] = &As[(p * 256 + w * 64) * 8];
        lB[p] = &Bs[(p * 256 + w * 64) * 8];
    }

    floatx4 acc[4][4];
#pragma unroll
    for (int i = 0; i < 4; ++i)
#pragma unroll
        for (int j = 0; j < 4; ++j) acc[i][j] = (floatx4){0.f, 0.f, 0.f, 0.f};

    int wr = (w >> 1) * 64, wc = (w & 1) * 64;
    int fr = l & 15, fq = l >> 4;

    for (int k0 = 0; k0 < DIMS; k0 += 64) {
#pragma unroll
        for (int p = 0; p < 4; ++p) {
            async16(lA[p], gA[p]); gA[p] += 64;
            async16(lB[p], gB[p]); gB[p] += 64;
        }
        __syncthreads();
#pragma unroll
        for (int kk = 0; kk < 2; ++kk) {
            int gc = kk * 4 + fq;
            half8 a[4], b[4];
#pragma unroll
            for (int i = 0; i < 4; ++i) {
                int r = wr + i * 16 + fr;
                a[i] = *(const half8*)&As[r * 64 + ((gc ^ (r & 7)) << 3)];
            }
#pragma unroll
            for (int j = 0; j < 4; ++j) {
                int r = wc + j * 16 + fr;
                b[j] = *(const half8*)&Bs[r * 64 + ((gc ^ (r & 7)) << 3)];
            }
#pragma unroll
            for (int i = 0; i < 4; ++i)
#pragma unroll
                for (int j = 0; j < 4; ++j)
                    acc[i][j] = __builtin_amdgcn_mfma_f32_16x16x32_f16(a[i], b[j], acc[i][j], 0, 0, 0);
        }
        __syncthreads();
    }

    // epilogue: u at frag j, g at frag j+2 (same lane) -> no shuffles
    int cq = l & 15, rq = (l >> 4) * 4;
    int nbase = (n0 + wc) >> 1;
    size_t hoff = routed ? HIDS : 0;
#pragma unroll
    for (int i = 0; i < 4; ++i) {
#pragma unroll
        for (int r = 0; r < 4; ++r) {
            int m = wr + i * 16 + rq + r;
            int tok = rowTok[m];
            if (tok < 0) continue;
            float sc = routed ? wtok[tok] : 1.f;
            ushort_t* hp = hcat + (size_t)tok * (2 * HIDS) + hoff + nbase;
#pragma unroll
            for (int j = 0; j < 2; ++j) {
                float u = acc[i][j][r], gg = acc[i][j + 2][r];
                float h = sc * u * (gg / (1.f + __expf(-gg)));
                hp[j * 16 + cq] = f2h(h);
            }
        }
    }
}

// ---------------- down GEMM 128m x 64n, K=8192 ([hs|hr] @ [Wds;Wde]) ----------------
// Single pass, single write to out: every token in exactly one group.
__global__ __launch_bounds__(256) void down_gemm(
    const ushort_t* __restrict__ hcat, const ushort_t* __restrict__ wdT,
    float* __restrict__ out,
    const int* __restrict__ lists, const int* __restrict__ counts)
{
    int e = blockIdx.z;
    int cnt = counts[e];
    int m0 = blockIdx.y * 128;
    if (m0 >= cnt) return;
    int n0 = blockIdx.x * 64;
    const ushort_t* BS = wdT + (size_t)NROUT * DIMS * HIDS;  // shared down
    const ushort_t* BE = wdT + (size_t)e * DIMS * HIDS;      // expert down

    __shared__ ushort_t As[128 * 64];  // 16 KB
    __shared__ ushort_t Bs[64 * 64];   //  8 KB
    __shared__ int rowTok[128];
    int t = threadIdx.x;
    if (t < 128) {
        int i = m0 + t;
        rowTok[t] = (i < cnt) ? lists[e * TNUM + i] : -1;
    }
    __syncthreads();

    int w = t >> 6, l = t & 63;
    const ushort_t* gA[4]; ushort_t* lA[4];
    size_t bOff[2]; ushort_t* lB[2];
#pragma unroll
    for (int p = 0; p < 4; ++p) {
        int slot = p * 256 + t, row = slot >> 3, ch = (slot & 7) ^ (row & 7);
        int tok = rowTok[row]; if (tok < 0) tok = 0;
        gA[p] = hcat + (size_t)tok * (2 * HIDS) + ch * 8;
        lA[p] = &As[(p * 256 + w * 64) * 8];
    }
#pragma unroll
    for (int q = 0; q < 2; ++q) {
        int slot = q * 256 + t, row = slot >> 3, ch = (slot & 7) ^ (row & 7);
        bOff[q] = (size_t)(n0 + row) * HIDS + ch * 8;
        lB[q] = &Bs[(q * 256 + w * 64) * 8];
    }

    floatx4 acc[4][2];
#pragma unroll
    for (int i = 0; i < 4; ++i)
#pragma unroll
        for (int j = 0; j < 2; ++j) acc[i][j] = (floatx4){0.f, 0.f, 0.f, 0.f};

    int wr = (w >> 1) * 64, wc = (w & 1) * 32;
    int fr = l & 15, fq = l >> 4;

#pragma unroll 1
    for (int half = 0; half < 2; ++half) {
        const ushort_t* Bsrc = half ? BE : BS;
        for (int k0 = 0; k0 < HIDS; k0 += 64) {
#pragma unroll
            for (int p = 0; p < 4; ++p) { async16(lA[p], gA[p]); gA[p] += 64; }
#pragma unroll
            for (int q = 0; q < 2; ++q) { async16(lB[q], Bsrc + bOff[q] + k0); }
            __syncthreads();
#pragma unroll
            for (int kk = 0; kk < 2; ++kk) {
                int gc = kk * 4 + fq;
                half8 a[4], b[2];
#pragma unroll
                for (int i = 0; i < 4; ++i) {
                    int r = wr + i * 16 + fr;
                    a[i] = *(const half8*)&As[r * 64 + ((gc ^ (r & 7)) << 3)];
                }
#pragma unroll
                for (int j = 0; j < 2; ++j) {
                    int r = wc + j * 16 + fr;
                    b[j] = *(const half8*)&Bs[r * 64 + ((gc ^ (r & 7)) << 3)];
                }
#pragma unroll
                for (int i = 0; i < 4; ++i)
#pragma unroll
                    for (int j = 0; j < 2; ++j)
                        acc[i][j] = __builtin_amdgcn_mfma_f32_16x16x32_f16(a[i], b[j], acc[i][j], 0, 0, 0);
            }
            __syncthreads();
        }
    }

    int cq = l & 15, rq = (l >> 4) * 4;
#pragma unroll
    for (int i = 0; i < 4; ++i) {
#pragma unroll
        for (int r = 0; r < 4; ++r) {
            int m = wr + i * 16 + rq + r;
            int tok = rowTok[m];
            if (tok < 0) continue;
            float* op = out + (size_t)tok * DIMS + n0 + wc;
#pragma unroll
            for (int j = 0; j < 2; ++j) op[j * 16 + cq] = acc[i][j][r];
        }
    }
}

extern "C" void kernel_launch(void* const* d_in, const int* in_sizes, int n_in,
                              void* d_out, int out_size, void* d_ws, size_t ws_size,
                              hipStream_t stream)
{
    const float* x  = (const float*)d_in[0];
    const float* wr = (const float*)d_in[1];
    const float* wu = (const float*)d_in[2];
    const float* wg = (const float*)d_in[3];
    const float* wd = (const float*)d_in[4];
    const float* su = (const float*)d_in[5];
    const float* sg = (const float*)d_in[6];
    const float* sd = (const float*)d_in[7];
    float* out = (float*)d_out;

    char* ws = (char*)d_ws;
    size_t off = 0;
    ushort_t* wugT = (ushort_t*)(ws + off); off += (size_t)NEXP * 2 * HIDS * DIMS * 2;  // 128 MB
    ushort_t* wdT  = (ushort_t*)(ws + off); off += (size_t)NEXP * DIMS * HIDS * 2;      //  64 MB
    ushort_t* x16  = (ushort_t*)(ws + off); off += (size_t)TNUM * DIMS * 2;             //   4 MB
    ushort_t* hcat = (ushort_t*)(ws + off); off += (size_t)TNUM * 2 * HIDS * 2;         //  32 MB
    float* wtok    = (float*)(ws + off);    off += TNUM * 4;
    int* idx       = (int*)(ws + off);      off += TNUM * 4;
    int* counts    = (int*)(ws + off);      off += 64;
    int* lists     = (int*)(ws + off);      off += (size_t)NROUT * TNUM * 4;

    router_kernel<<<TNUM / 4, 256, 0, stream>>>(x, wr, idx, wtok);
    zero_counts_kernel<<<1, 64, 0, stream>>>(counts);
    build_lists_kernel<<<TNUM / 256, 256, 0, stream>>>(idx, counts, lists);
    x2h_kernel<<<TNUM * DIMS / 1024, 256, 0, stream>>>(x, x16);
    repack_kernel<<<24576, 256, 0, stream>>>(wu, wg, wd, su, sg, sd, wugT, wdT);

    upgate_gemm<<<dim3(2 * HIDS / 128, TNUM / 128, NEXP), 256, 0, stream>>>(
        x16, wugT, hcat, lists, counts, wtok);
    down_gemm<<<dim3(DIMS / 64, TNUM / 128, NROUT), 256, 0, stream>>>(
        hcat, wdT, out, lists, counts);
}

// Round 4
// 628.869 us; speedup vs baseline: 1.3144x; 1.1074x over previous
//
#include <hip/hip_runtime.h>
#include <hip/hip_fp16.h>

#define TNUM 2048
#define DIMS 1024
#define HIDS 4096
#define NEXP 8
#define NROUT 7
#define ALPHAF 2.0f

typedef __attribute__((ext_vector_type(4))) float floatx4;
typedef _Float16 half8 __attribute__((ext_vector_type(8)));
typedef unsigned short ushort_t;

static __device__ __forceinline__ ushort_t f2h(float f) {
    return __half_as_ushort(__float2half(f));
}

// async 16B global -> LDS. lds base wave-uniform; HW adds lane*16.
static __device__ __forceinline__ void async16(ushort_t* lds, const ushort_t* g) {
#if __has_builtin(__builtin_amdgcn_global_load_lds)
    __builtin_amdgcn_global_load_lds(
        (const __attribute__((address_space(1))) unsigned int*)g,
        (__attribute__((address_space(3))) unsigned int*)lds, 16, 0, 0);
#else
    int l = threadIdx.x & 63;
    *(uint4*)(lds + l * 8) = *(const uint4*)g;
#endif
}

// ---------------- router: fp32 logits, softmax, top-1 ----------------
// best==7 (no routed expert) -> expert 0 with weight 0, so every token is in
// exactly one routed group (single-write down pass).
__global__ __launch_bounds__(256) void router_kernel(
    const float* __restrict__ x, const float* __restrict__ wr,
    int* __restrict__ idx, float* __restrict__ wtok)
{
    int tok = blockIdx.x * 4 + (threadIdx.x >> 6);
    int lane = threadIdx.x & 63;
    const float* xp = x + (size_t)tok * DIMS;
    float acc[NEXP];
#pragma unroll
    for (int e = 0; e < NEXP; ++e) acc[e] = 0.f;
    for (int d = lane; d < DIMS; d += 64) {
        float xv = xp[d];
        const float* wrow = wr + d * NEXP;
#pragma unroll
        for (int e = 0; e < NEXP; ++e) acc[e] += xv * wrow[e];
    }
#pragma unroll
    for (int off = 32; off > 0; off >>= 1) {
#pragma unroll
        for (int e = 0; e < NEXP; ++e) acc[e] += __shfl_xor(acc[e], off, 64);
    }
    if (lane == 0) {
        float mx = acc[0];
#pragma unroll
        for (int e = 1; e < NEXP; ++e) mx = fmaxf(mx, acc[e]);
        float s = 0.f, pe[NEXP];
#pragma unroll
        for (int e = 0; e < NEXP; ++e) { pe[e] = __expf(acc[e] - mx); s += pe[e]; }
        int best = 0; float bv = acc[0];
#pragma unroll
        for (int e = 1; e < NEXP; ++e) if (acc[e] > bv) { bv = acc[e]; best = e; }
        if (best == NROUT) { idx[tok] = 0; wtok[tok] = 0.f; }
        else               { idx[tok] = best; wtok[tok] = ALPHAF * pe[best] / s; }
    }
}

__global__ void zero_counts_kernel(int* counts) {
    if (threadIdx.x < NROUT) counts[threadIdx.x] = 0;
}

__global__ __launch_bounds__(256) void build_lists_kernel(
    const int* __restrict__ idx, int* __restrict__ counts, int* __restrict__ lists)
{
    int t = blockIdx.x * 256 + threadIdx.x;
    int e = idx[t];
    int pos = atomicAdd(&counts[e], 1);
    lists[e * TNUM + pos] = t;
}

// ---------------- x fp32 -> f16 ----------------
__global__ __launch_bounds__(256) void x2h_kernel(
    const float* __restrict__ x, ushort_t* __restrict__ x16)
{
    int i = (blockIdx.x * 256 + threadIdx.x) * 4;
    float4 v = *(const float4*)(x + i);
    ushort_t tmp[4] = { f2h(v.x), f2h(v.y), f2h(v.z), f2h(v.w) };
    *(uint2*)(x16 + i) = *(const uint2*)tmp;
}

// ---------------- weight repack: f32 [K][N] -> f16 [R(n)][K] ----------------
// 128x128 tiles. up/gate rows per 64-group G: G*64+0..31 = up cols G*32+..,
// G*64+32..63 = gate cols. down: plain [n][k]. Expert 7 = shared.
// Grid: 4096 ug blocks (16 slices x 32 nt x 8 kt) + 2048 down (8 x 8 nt x 32 kt).
#define LDK 136
__global__ __launch_bounds__(256) void repack_kernel(
    const float* __restrict__ wu, const float* __restrict__ wg, const float* __restrict__ wd,
    const float* __restrict__ su, const float* __restrict__ sg, const float* __restrict__ sd,
    ushort_t* __restrict__ wugT, ushort_t* __restrict__ wdT)
{
    int g = blockIdx.x;
    const float* src; ushort_t* dst; int N, K, gateAdd; bool ug;
    int nt, kt;
    if (g < 4096) {                          // up/gate: K=1024 (8 kt), N=4096 (32 nt)
        int slice = g >> 8, r = g & 255;
        nt = r >> 3; kt = r & 7;
        K = DIMS; N = HIDS; ug = true;
        if (slice < 7)        { src = wu + (size_t)slice * DIMS * HIDS;       dst = wugT + (size_t)slice * 2 * HIDS * DIMS; gateAdd = 0; }
        else if (slice < 14)  { src = wg + (size_t)(slice - 7) * DIMS * HIDS; dst = wugT + (size_t)(slice - 7) * 2 * HIDS * DIMS; gateAdd = 32; }
        else if (slice == 14) { src = su; dst = wugT + (size_t)7 * 2 * HIDS * DIMS; gateAdd = 0; }
        else                  { src = sg; dst = wugT + (size_t)7 * 2 * HIDS * DIMS; gateAdd = 32; }
    } else {                                 // down: K=4096 (32 kt), N=1024 (8 nt)
        int gd = g - 4096; int slice = gd >> 8, r = gd & 255;
        nt = r & 7; kt = r >> 3;
        K = HIDS; N = DIMS; ug = false; gateAdd = 0;
        if (slice < 7) { src = wd + (size_t)slice * HIDS * DIMS; dst = wdT + (size_t)slice * DIMS * HIDS; }
        else           { src = sd;                               dst = wdT + (size_t)7 * DIMS * HIDS; }
    }
    int n0 = nt * 128, k0 = kt * 128;

    __shared__ ushort_t T[128 * LDK];   // [n][k] f16
    int t = threadIdx.x;
    int kr = t >> 1, nc = (t & 1) * 64;
    const float* sp = src + (size_t)(k0 + kr) * N + n0 + nc;
    float v[64];
#pragma unroll
    for (int q = 0; q < 16; ++q)
        *(float4*)&v[q * 4] = *(const float4*)(sp + q * 4);
#pragma unroll
    for (int j = 0; j < 64; ++j)
        T[(nc + j) * LDK + kr] = f2h(v[j]);
    __syncthreads();

    int rn = t >> 1, kc = (t & 1) * 64;
    int n = n0 + rn;
    size_t R = ug ? (size_t)(((n >> 5) << 6) + (n & 31) + gateAdd) : (size_t)n;
    ushort_t* dp = dst + R * K + k0 + kc;
#pragma unroll
    for (int q = 0; q < 8; ++q)
        *(uint4*)(dp + q * 8) = *(const uint4*)&T[rn * LDK + kc + q * 8];
}

// ---------------- up/gate GEMM 128x128, BK=64, swizzled LDS ----------------
// z = expert (7 = shared over all tokens). h = [wtok *] u*silu(g) ->
// hcat[tok][8192]: shared half [0,4096), routed half [4096,8192).
__global__ __launch_bounds__(256) void upgate_gemm(
    const ushort_t* __restrict__ x16, const ushort_t* __restrict__ wugT,
    ushort_t* __restrict__ hcat,
    const int* __restrict__ lists, const int* __restrict__ counts,
    const float* __restrict__ wtok)
{
    int e = blockIdx.z;
    bool routed = e < NROUT;
    int cnt = routed ? counts[e] : TNUM;
    int m0 = blockIdx.y * 128;
    if (m0 >= cnt) return;
    int n0 = blockIdx.x * 128;
    const ushort_t* B = wugT + (size_t)e * 2 * HIDS * DIMS;

    __shared__ ushort_t As[128 * 64];
    __shared__ ushort_t Bs[128 * 64];
    __shared__ int rowTok[128];
    int t = threadIdx.x;
    if (t < 128) {
        int i = m0 + t;
        rowTok[t] = (i < cnt) ? (routed ? lists[e * TNUM + i] : i) : -1;
    }
    __syncthreads();

    int w = t >> 6, l = t & 63;
    const ushort_t *gA[4], *gB[4]; ushort_t *lA[4], *lB[4];
#pragma unroll
    for (int p = 0; p < 4; ++p) {
        int slot = p * 256 + t, row = slot >> 3, ch = (slot & 7) ^ (row & 7);
        int tok = rowTok[row]; if (tok < 0) tok = 0;
        gA[p] = x16 + (size_t)tok * DIMS + ch * 8;
        gB[p] = B + (size_t)(n0 + row) * DIMS + ch * 8;
        lA[p] = &As[(p * 256 + w * 64) * 8];
        lB[p] = &Bs[(p * 256 + w * 64) * 8];
    }

    floatx4 acc[4][4];
#pragma unroll
    for (int i = 0; i < 4; ++i)
#pragma unroll
        for (int j = 0; j < 4; ++j) acc[i][j] = (floatx4){0.f, 0.f, 0.f, 0.f};

    int wr = (w >> 1) * 64, wc = (w & 1) * 64;
    int fr = l & 15, fq = l >> 4;

    for (int k0 = 0; k0 < DIMS; k0 += 64) {
#pragma unroll
        for (int p = 0; p < 4; ++p) {
            async16(lA[p], gA[p]); gA[p] += 64;
            async16(lB[p], gB[p]); gB[p] += 64;
        }
        __syncthreads();
#pragma unroll
        for (int kk = 0; kk < 2; ++kk) {
            int gc = kk * 4 + fq;
            half8 a[4], b[4];
#pragma unroll
            for (int i = 0; i < 4; ++i) {
                int r = wr + i * 16 + fr;
                a[i] = *(const half8*)&As[r * 64 + ((gc ^ (r & 7)) << 3)];
            }
#pragma unroll
            for (int j = 0; j < 4; ++j) {
                int r = wc + j * 16 + fr;
                b[j] = *(const half8*)&Bs[r * 64 + ((gc ^ (r & 7)) << 3)];
            }
#pragma unroll
            for (int i = 0; i < 4; ++i)
#pragma unroll
                for (int j = 0; j < 4; ++j)
                    acc[i][j] = __builtin_amdgcn_mfma_f32_16x16x32_f16(a[i], b[j], acc[i][j], 0, 0, 0);
        }
        __syncthreads();
    }

    // epilogue: u at frag j, g at frag j+2 (same lane) -> no shuffles
    int cq = l & 15, rq = (l >> 4) * 4;
    int nbase = (n0 + wc) >> 1;
    size_t hoff = routed ? HIDS : 0;
#pragma unroll
    for (int i = 0; i < 4; ++i) {
#pragma unroll
        for (int r = 0; r < 4; ++r) {
            int m = wr + i * 16 + rq + r;
            int tok = rowTok[m];
            if (tok < 0) continue;
            float sc = routed ? wtok[tok] : 1.f;
            ushort_t* hp = hcat + (size_t)tok * (2 * HIDS) + hoff + nbase;
#pragma unroll
            for (int j = 0; j < 2; ++j) {
                float u = acc[i][j][r], gg = acc[i][j + 2][r];
                float h = sc * u * (gg / (1.f + __expf(-gg)));
                hp[j * 16 + cq] = f2h(h);
            }
        }
    }
}

// ---------------- down GEMM 128x128, split-K=4 over concat K=8192 ----------------
// z = e*4 + s. s=0,1 -> shared weight half, s=2,3 -> expert half.
// Writes fp32 partials part[s][tok][d]; reduce_kernel sums them.
__global__ __launch_bounds__(256) void down_gemm(
    const ushort_t* __restrict__ hcat, const ushort_t* __restrict__ wdT,
    float* __restrict__ part,
    const int* __restrict__ lists, const int* __restrict__ counts)
{
    int z = blockIdx.z;
    int e = z >> 2, s = z & 3;
    int cnt = counts[e];
    int m0 = blockIdx.y * 128;
    if (m0 >= cnt) return;
    int n0 = blockIdx.x * 128;
    const ushort_t* B = (s < 2)
        ? wdT + (size_t)NROUT * DIMS * HIDS + (size_t)s * 2048
        : wdT + (size_t)e * DIMS * HIDS + (size_t)(s - 2) * 2048;
    size_t aoff = (size_t)s * 2048;

    __shared__ ushort_t As[128 * 64];
    __shared__ ushort_t Bs[128 * 64];
    __shared__ int rowTok[128];
    int t = threadIdx.x;
    if (t < 128) {
        int i = m0 + t;
        rowTok[t] = (i < cnt) ? lists[e * TNUM + i] : -1;
    }
    __syncthreads();

    int w = t >> 6, l = t & 63;
    const ushort_t *gA[4], *gB[4]; ushort_t *lA[4], *lB[4];
#pragma unroll
    for (int p = 0; p < 4; ++p) {
        int slot = p * 256 + t, row = slot >> 3, ch = (slot & 7) ^ (row & 7);
        int tok = rowTok[row]; if (tok < 0) tok = 0;
        gA[p] = hcat + (size_t)tok * (2 * HIDS) + aoff + ch * 8;
        gB[p] = B + (size_t)(n0 + row) * HIDS + ch * 8;
        lA[p] = &As[(p * 256 + w * 64) * 8];
        lB[p] = &Bs[(p * 256 + w * 64) * 8];
    }

    floatx4 acc[4][4];
#pragma unroll
    for (int i = 0; i < 4; ++i)
#pragma unroll
        for (int j = 0; j < 4; ++j) acc[i][j] = (floatx4){0.f, 0.f, 0.f, 0.f};

    int wr = (w >> 1) * 64, wc = (w & 1) * 64;
    int fr = l & 15, fq = l >> 4;

    for (int k0 = 0; k0 < 2048; k0 += 64) {
#pragma unroll
        for (int p = 0; p < 4; ++p) {
            async16(lA[p], gA[p]); gA[p] += 64;
            async16(lB[p], gB[p]); gB[p] += 64;
        }
        __syncthreads();
#pragma unroll
        for (int kk = 0; kk < 2; ++kk) {
            int gc = kk * 4 + fq;
            half8 a[4], b[4];
#pragma unroll
            for (int i = 0; i < 4; ++i) {
                int r = wr + i * 16 + fr;
                a[i] = *(const half8*)&As[r * 64 + ((gc ^ (r & 7)) << 3)];
            }
#pragma unroll
            for (int j = 0; j < 4; ++j) {
                int r = wc + j * 16 + fr;
                b[j] = *(const half8*)&Bs[r * 64 + ((gc ^ (r & 7)) << 3)];
            }
#pragma unroll
            for (int i = 0; i < 4; ++i)
#pragma unroll
                for (int j = 0; j < 4; ++j)
                    acc[i][j] = __builtin_amdgcn_mfma_f32_16x16x32_f16(a[i], b[j], acc[i][j], 0, 0, 0);
        }
        __syncthreads();
    }

    int cq = l & 15, rq = (l >> 4) * 4;
#pragma unroll
    for (int i = 0; i < 4; ++i) {
#pragma unroll
        for (int r = 0; r < 4; ++r) {
            int m = wr + i * 16 + rq + r;
            int tok = rowTok[m];
            if (tok < 0) continue;
            float* pp = part + ((size_t)s * TNUM + tok) * DIMS + n0 + wc;
#pragma unroll
            for (int j = 0; j < 4; ++j) pp[j * 16 + cq] = acc[i][j][r];
        }
    }
}

// ---------------- reduce: out = sum of 4 partials ----------------
__global__ __launch_bounds__(256) void reduce_kernel(
    const float* __restrict__ part, float* __restrict__ out)
{
    size_t i = ((size_t)blockIdx.x * 256 + threadIdx.x) * 4;
    float4 a = *(const float4*)(part + i);
    float4 b = *(const float4*)(part + (size_t)TNUM * DIMS + i);
    float4 c = *(const float4*)(part + (size_t)2 * TNUM * DIMS + i);
    float4 d = *(const float4*)(part + (size_t)3 * TNUM * DIMS + i);
    float4 o = make_float4(a.x + b.x + c.x + d.x, a.y + b.y + c.y + d.y,
                           a.z + b.z + c.z + d.z, a.w + b.w + c.w + d.w);
    *(float4*)(out + i) = o;
}

extern "C" void kernel_launch(void* const* d_in, const int* in_sizes, int n_in,
                              void* d_out, int out_size, void* d_ws, size_t ws_size,
                              hipStream_t stream)
{
    const float* x  = (const float*)d_in[0];
    const float* wr = (const float*)d_in[1];
    const float* wu = (const float*)d_in[2];
    const float* wg = (const float*)d_in[3];
    const float* wd = (const float*)d_in[4];
    const float* su = (const float*)d_in[5];
    const float* sg = (const float*)d_in[6];
    const float* sd = (const float*)d_in[7];
    float* out = (float*)d_out;

    char* ws = (char*)d_ws;
    size_t off = 0;
    ushort_t* wugT = (ushort_t*)(ws + off); off += (size_t)NEXP * 2 * HIDS * DIMS * 2;  // 128 MB
    ushort_t* wdT  = (ushort_t*)(ws + off); off += (size_t)NEXP * DIMS * HIDS * 2;      //  64 MB
    ushort_t* x16  = (ushort_t*)(ws + off); off += (size_t)TNUM * DIMS * 2;             //   4 MB
    ushort_t* hcat = (ushort_t*)(ws + off); off += (size_t)TNUM * 2 * HIDS * 2;         //  32 MB
    float* part    = (float*)(ws + off);    off += (size_t)4 * TNUM * DIMS * 4;         //  32 MB
    float* wtok    = (float*)(ws + off);    off += TNUM * 4;
    int* idx       = (int*)(ws + off);      off += TNUM * 4;
    int* counts    = (int*)(ws + off);      off += 64;
    int* lists     = (int*)(ws + off);      off += (size_t)NROUT * TNUM * 4;

    router_kernel<<<TNUM / 4, 256, 0, stream>>>(x, wr, idx, wtok);
    zero_counts_kernel<<<1, 64, 0, stream>>>(counts);
    build_lists_kernel<<<TNUM / 256, 256, 0, stream>>>(idx, counts, lists);
    x2h_kernel<<<TNUM * DIMS / 1024, 256, 0, stream>>>(x, x16);
    repack_kernel<<<6144, 256, 0, stream>>>(wu, wg, wd, su, sg, sd, wugT, wdT);

    upgate_gemm<<<dim3(2 * HIDS / 128, TNUM / 128, NEXP), 256, 0, stream>>>(
        x16, wugT, hcat, lists, counts, wtok);
    down_gemm<<<dim3(DIMS / 128, TNUM / 128, NROUT * 4), 256, 0, stream>>>(
        hcat, wdT, part, lists, counts);
    reduce_kernel<<<TNUM * DIMS / 1024, 256, 0, stream>>>(part, out);
}